// Round 1
// baseline (44.057 us; speedup 1.0000x reference)
//
#include <hip/hip_runtime.h>

// Problem constants (reference: B=8, T=2000, N=2048, penalty=10.0)
#define B_CONST 8
#define T_CONST 2000
#define N_CONST 2048
#define COUT 10                       // grid.z chunks
#define CIN 4                         // chunks per block (one per wave row)
#define TC (T_CONST / (COUT * CIN))   // 50 timesteps per thread
#define PENALTY 10.0f

// Partial per (b, n, chunk): (count, t_first, t_last, sum ISI^2) packed in float4.
// Monoid combine: if both nonempty, s2 += (R.first - L.last)^2; first=L.first, last=R.last.

__global__ __launch_bounds__(256) void cv_partial_kernel(const float* __restrict__ x,
                                                         float4* __restrict__ ws) {
    const int l  = threadIdx.x & 63;   // lane -> 4 consecutive n
    const int c  = threadIdx.x >> 6;   // in-block chunk 0..3
    const int nb = blockIdx.x;         // n-block (256 n each)
    const int b  = blockIdx.y;
    const int zc = blockIdx.z;         // outer chunk 0..9
    const int cc = zc * CIN + c;       // global chunk 0..39
    const int n0 = nb * 256 + l * 4;
    const int t0 = cc * TC;

    const float* p = x + ((size_t)b * T_CONST + t0) * (size_t)N_CONST + n0;

    float cnt[4]  = {0.f, 0.f, 0.f, 0.f};
    float frst[4] = {0.f, 0.f, 0.f, 0.f};
    float last[4] = {0.f, 0.f, 0.f, 0.f};
    float s2[4]   = {0.f, 0.f, 0.f, 0.f};

#pragma unroll 5
    for (int i = 0; i < TC; ++i) {
        const float4 v = *reinterpret_cast<const float4*>(p);
        p += N_CONST;
        const float t = (float)(t0 + i);
        const float vv[4] = {v.x, v.y, v.z, v.w};
#pragma unroll
        for (int j = 0; j < 4; ++j) {
            if (vv[j] > 0.0f) {                       // spike
                const float d = t - last[j];
                s2[j]  += (cnt[j] > 0.0f) ? d * d : 0.0f;
                frst[j] = (cnt[j] > 0.0f) ? frst[j] : t;
                last[j] = t;
                cnt[j] += 1.0f;
            }
        }
    }

    // merge the 4 in-block chunks (ascending time order) via LDS
    __shared__ float4 lds[CIN][64][4];
#pragma unroll
    for (int j = 0; j < 4; ++j)
        lds[c][l][j] = make_float4(cnt[j], frst[j], last[j], s2[j]);
    __syncthreads();

    if (c == 0) {
#pragma unroll
        for (int j = 0; j < 4; ++j) {
            float mc = 0.f, mf = 0.f, ml = 0.f, ms = 0.f;
#pragma unroll
            for (int q = 0; q < CIN; ++q) {
                const float4 pp = lds[q][l][j];
                if (pp.x > 0.0f) {
                    if (mc > 0.0f) {
                        const float d = pp.y - ml;   // cross-chunk ISI
                        ms += pp.w + d * d;
                        ml  = pp.z;
                        mc += pp.x;
                    } else {
                        mc = pp.x; mf = pp.y; ml = pp.z; ms = pp.w;
                    }
                }
            }
            ws[((size_t)(b * COUT + zc) * N_CONST) + n0 + j] =
                make_float4(mc, mf, ml, ms);
        }
    }
}

__global__ __launch_bounds__(256) void cv_final_kernel(const float4* __restrict__ ws,
                                                       const float* __restrict__ tcv,
                                                       float* __restrict__ out) {
    const int gid = blockIdx.x * 256 + threadIdx.x;  // 0 .. B*N-1
    const int b   = gid >> 11;                       // / N_CONST
    const int n   = gid & (N_CONST - 1);

    float mc = 0.f, mf = 0.f, ml = 0.f, ms = 0.f;
#pragma unroll
    for (int q = 0; q < COUT; ++q) {
        const float4 pp = ws[((size_t)(b * COUT + q) * N_CONST) + n];
        if (pp.x > 0.0f) {
            if (mc > 0.0f) {
                const float d = pp.y - ml;
                ms += pp.w + d * d;
                ml  = pp.z;
                mc += pp.x;
            } else {
                mc = pp.x; mf = pp.y; ml = pp.z; ms = pp.w;
            }
        }
    }

    float cvs;
    if (mc >= 3.0f) {                       // count>=3 implies mean_isi>0 (integer times)
        const float k    = mc - 1.0f;       // number of ISIs
        const float s1   = ml - mf;         // telescoped sum of ISIs
        const float mean = s1 / k;
        float var = (ms - k * mean * mean) / (k - 1.0f);   // unbiased, same formula as ref
        var = fmaxf(var, 0.0f);
        cvs = sqrtf(var) / mean;
    } else {
        cvs = PENALTY;
    }
    const float dd = cvs - tcv[n];
    float e = dd * dd;

    // wave64 shuffle reduce, then cross-wave via LDS, one atomic per block
#pragma unroll
    for (int o = 32; o > 0; o >>= 1) e += __shfl_down(e, o, 64);
    __shared__ float wred[4];
    if ((threadIdx.x & 63) == 0) wred[threadIdx.x >> 6] = e;
    __syncthreads();
    if (threadIdx.x == 0) {
        const float s = (wred[0] + wred[1] + wred[2] + wred[3]) *
                        (1.0f / ((float)B_CONST * (float)N_CONST));
        atomicAdd(out, s);
    }
}

extern "C" void kernel_launch(void* const* d_in, const int* in_sizes, int n_in,
                              void* d_out, int out_size, void* d_ws, size_t ws_size,
                              hipStream_t stream) {
    const float* x   = (const float*)d_in[0];   // (B,T,N) fp32
    const float* tcv = (const float*)d_in[1];   // (N,) fp32
    float* out = (float*)d_out;
    float4* ws = (float4*)d_ws;                 // needs B*COUT*N*16 = 2.6 MB

    hipMemsetAsync(d_out, 0, sizeof(float), stream);

    dim3 g1(N_CONST / 256, B_CONST, COUT);
    cv_partial_kernel<<<g1, dim3(256), 0, stream>>>(x, ws);

    cv_final_kernel<<<(B_CONST * N_CONST) / 256, dim3(256), 0, stream>>>(ws, tcv, out);
}